// Round 4
// baseline (211.806 us; speedup 1.0000x reference)
//
#include <hip/hip_runtime.h>
#include <hip/hip_bf16.h>
#include <math.h>

typedef __bf16 bf16x8 __attribute__((ext_vector_type(8)));
typedef float  f32x4  __attribute__((ext_vector_type(4)));

#define B_    2
#define N_    2048
#define H_    16
#define D_    64
#define HD    (H_ * D_)
#define QSCALE (0.125f * 1.44269504089f)   // 1/sqrt(64) * log2(e): softmax in exp2 domain
#define THR   8.0f                          // defer-max threshold (log2 units, P <= 2^8)
#define KVBLK 64
#define QBLK  128
#define CVT_SZ (8388608ull)                 // B*N*H*D * 2 bytes

#if __has_builtin(__builtin_amdgcn_exp2f)
#define EXP2F(x) __builtin_amdgcn_exp2f(x)
#else
#define EXP2F(x) __expf(0.69314718056f * (x))
#endif

// ---------------- pre-pass (one launch): K -> bf16 [b][h][n][d]; V -> bf16 [b][h][d][n] ----
__global__ __launch_bounds__(256) void prep_kernel(
    const float* __restrict__ k, const float* __restrict__ v,
    __bf16* __restrict__ kb, __bf16* __restrict__ vt)
{
    __shared__ float tile[64][65];
    const int bid = blockIdx.x;
    const int tid = threadIdx.x;
    if (bid < 2048) {
        // K: [b][n][h][d] fp32 -> [b][h][n][d] bf16
        int t = bid * 256 + tid;
        int r = t >> 3;
        int j = (t & 7) * 8;
        int b = r >> 15;
        int rem = r & 32767;
        int n = rem >> 4;
        int h = rem & 15;
        const float* s = k + (size_t)r * D_ + j;
        f32x4 v0 = *(const f32x4*)s;
        f32x4 v1 = *(const f32x4*)(s + 4);
        bf16x8 o;
        #pragma unroll
        for (int e = 0; e < 4; ++e) { o[e] = (__bf16)v0[e]; o[4 + e] = (__bf16)v1[e]; }
        *(bf16x8*)(kb + ((size_t)(b * H_ + h) * N_ + n) * D_ + j) = o;
    } else {
        // V: [b][n][h][d] fp32 -> transposed [b][h][d][n] bf16
        int vb = bid - 2048;              // 0..1023
        int n0 = (vb & 31) * 64;
        int h  = (vb >> 5) & 15;
        int b  = vb >> 9;
        const float* vp = v + (size_t)b * N_ * HD + (size_t)h * D_;
        #pragma unroll
        for (int rep = 0; rep < 4; ++rep) {
            int idx = rep * 256 + tid;
            int i  = idx >> 4;
            int c4 = (idx & 15) * 4;
            f32x4 x = *(const f32x4*)(vp + (size_t)(n0 + i) * HD + c4);
            tile[i][c4] = x[0]; tile[i][c4 + 1] = x[1]; tile[i][c4 + 2] = x[2]; tile[i][c4 + 3] = x[3];
        }
        __syncthreads();
        __bf16* vtp = vt + ((size_t)(b * H_ + h) * D_) * N_ + n0;
        #pragma unroll
        for (int rep = 0; rep < 2; ++rep) {
            int idx = rep * 256 + tid;
            int d  = idx >> 3;
            int s8 = (idx & 7) * 8;
            bf16x8 o;
            #pragma unroll
            for (int j2 = 0; j2 < 8; ++j2) o[j2] = (__bf16)tile[s8 + j2][d];
            *(bf16x8*)(vtp + (size_t)d * N_ + s8) = o;
        }
    }
}

// ---------------- per-KV-tile body: prefetch next K, compute QK/softmax/PV ----------
__device__ __forceinline__ void tile_body(
    const __bf16* __restrict__ kp, const __bf16* __restrict__ vp, int kv0,
    bf16x8 (&kcur)[4][2], bf16x8 (&knxt)[4][2],
    const bf16x8 (&qa)[2][2], float (&m)[2][4], float (&l)[2][4],
    f32x4 (&o)[2][4], __bf16 (*pl)[72], int lo, int hi)
{
    const int kvn = (kv0 + KVBLK) & (N_ - 1);   // wrapped prefetch (last iter loads tile 0, unused)
    // V for this tile: issued early, used after QK+softmax (~300 cy) -> latency covered
    bf16x8 vf[4][2];
    #pragma unroll
    for (int f = 0; f < 4; ++f)
        #pragma unroll
        for (int s2 = 0; s2 < 2; ++s2)
            vf[f][s2] = *(const bf16x8*)(vp + (size_t)(f * 16 + lo) * N_ + kv0 + s2 * 32 + hi * 8);
    // K for NEXT tile
    #pragma unroll
    for (int c = 0; c < 4; ++c)
        #pragma unroll
        for (int kk = 0; kk < 2; ++kk)
            knxt[c][kk] = *(const bf16x8*)(kp + (size_t)(kvn + c * 16 + lo) * D_ + kk * 32 + hi * 8);

    #pragma unroll
    for (int rb = 0; rb < 2; ++rb) {
        // S[16][64] in exp2 domain (Q pre-scaled by 1/sqrt(d)*log2e)
        f32x4 s[4];
        #pragma unroll
        for (int c = 0; c < 4; ++c) {
            s[c] = (f32x4)0.f;
            #pragma unroll
            for (int kk = 0; kk < 2; ++kk)
                s[c] = __builtin_amdgcn_mfma_f32_16x16x32_bf16(qa[rb][kk], kcur[c][kk], s[c], 0, 0, 0);
        }
        // T13 defer-max: skip shuffle-reduce + rescale when max doesn't grow past THR
        float pm[4];
        #pragma unroll
        for (int r = 0; r < 4; ++r)
            pm[r] = fmaxf(fmaxf(s[0][r], s[1][r]), fmaxf(s[2][r], s[3][r]));
        int ok = (pm[0] <= m[rb][0] + THR) & (pm[1] <= m[rb][1] + THR)
               & (pm[2] <= m[rb][2] + THR) & (pm[3] <= m[rb][3] + THR);
        if (!__all(ok)) {
            #pragma unroll
            for (int r = 0; r < 4; ++r) {
                float tmax = pm[r];
                #pragma unroll
                for (int msk = 1; msk <= 8; msk <<= 1)
                    tmax = fmaxf(tmax, __shfl_xor(tmax, msk, 64));
                float mn = fmaxf(m[rb][r], tmax);
                float a  = EXP2F(m[rb][r] - mn);
                m[rb][r] = mn;
                l[rb][r] *= a;
                #pragma unroll
                for (int f = 0; f < 4; ++f) o[rb][f][r] *= a;
            }
        }
        #pragma unroll
        for (int r = 0; r < 4; ++r) {
            float p0 = EXP2F(s[0][r] - m[rb][r]);
            float p1 = EXP2F(s[1][r] - m[rb][r]);
            float p2 = EXP2F(s[2][r] - m[rb][r]);
            float p3 = EXP2F(s[3][r] - m[rb][r]);
            l[rb][r] += (p0 + p1) + (p2 + p3);
            pl[hi * 4 + r][lo]      = (__bf16)p0;
            pl[hi * 4 + r][16 + lo] = (__bf16)p1;
            pl[hi * 4 + r][32 + lo] = (__bf16)p2;
            pl[hi * 4 + r][48 + lo] = (__bf16)p3;
        }
        // wave-synchronous LDS transpose (in-order per-wave LDS pipe)
        __asm__ volatile("" ::: "memory");
        bf16x8 pa0 = *(const bf16x8*)&pl[lo][hi * 8];
        bf16x8 pa1 = *(const bf16x8*)&pl[lo][32 + hi * 8];
        __asm__ volatile("" ::: "memory");
        #pragma unroll
        for (int f = 0; f < 4; ++f) {
            o[rb][f] = __builtin_amdgcn_mfma_f32_16x16x32_bf16(pa0, vf[f][0], o[rb][f], 0, 0, 0);
            o[rb][f] = __builtin_amdgcn_mfma_f32_16x16x32_bf16(pa1, vf[f][1], o[rb][f], 0, 0, 0);
        }
    }
}

// ---------------- main flash-attention kernel ----------
__global__ __launch_bounds__(256) void attn_fwd_v3(
    const float* __restrict__ q,             // original [b][n][h][d] fp32
    const __bf16* __restrict__ kb,           // [b][h][n][d] bf16
    const __bf16* __restrict__ vt,           // [b][h][d][n] bf16
    float* __restrict__ out)                 // [b][n][h][d]
{
    const int tid  = threadIdx.x;
    const int lane = tid & 63;
    const int w    = tid >> 6;
    const int lo   = lane & 15;
    const int hi   = lane >> 4;

    // bijective XCD swizzle: 512 blocks = 8 XCDs x 64; each XCD owns 4 (b,h)
    int bid = blockIdx.x;
    int wg  = (bid & 7) * 64 + (bid >> 3);
    int qt  = wg & 15;
    int bh  = wg >> 4;
    int h   = bh & 15;
    int b   = bh >> 4;

    __shared__ __align__(16) __bf16 p_lds[4][16][72];

    const size_t bh_off = ((size_t)b * H_ + h) * (size_t)(N_ * D_);
    const __bf16* kp = kb + bh_off;
    const __bf16* vp = vt + bh_off;

    const int q0 = qt * QBLK + w * 32;

    // Q: direct fp32 load from original layout, convert+scale inline (read once)
    bf16x8 qa[2][2];
    #pragma unroll
    for (int rb = 0; rb < 2; ++rb)
        #pragma unroll
        for (int kk = 0; kk < 2; ++kk) {
            const float* qsrc = q + ((size_t)(b * N_ + q0 + rb * 16 + lo) * H_ + h) * D_ + kk * 32 + hi * 8;
            f32x4 a0 = *(const f32x4*)qsrc;
            f32x4 a1 = *(const f32x4*)(qsrc + 4);
            #pragma unroll
            for (int j = 0; j < 4; ++j) {
                qa[rb][kk][j]     = (__bf16)(a0[j] * QSCALE);
                qa[rb][kk][4 + j] = (__bf16)(a1[j] * QSCALE);
            }
        }

    float m[2][4], l[2][4];
    f32x4 o[2][4];
    #pragma unroll
    for (int rb = 0; rb < 2; ++rb)
        #pragma unroll
        for (int r = 0; r < 4; ++r) { m[rb][r] = -INFINITY; l[rb][r] = 0.f; }
    #pragma unroll
    for (int rb = 0; rb < 2; ++rb)
        #pragma unroll
        for (int f = 0; f < 4; ++f) o[rb][f] = (f32x4)0.f;

    // preload K tile 0; then double-buffered loop (static names, rule-20 safe)
    bf16x8 kfA[4][2], kfB[4][2];
    #pragma unroll
    for (int c = 0; c < 4; ++c)
        #pragma unroll
        for (int kk = 0; kk < 2; ++kk)
            kfA[c][kk] = *(const bf16x8*)(kp + (size_t)(c * 16 + lo) * D_ + kk * 32 + hi * 8);

    for (int t = 0; t < N_ / KVBLK; t += 2) {
        tile_body(kp, vp, t * KVBLK,       kfA, kfB, qa, m, l, o, p_lds[w], lo, hi);
        tile_body(kp, vp, (t + 1) * KVBLK, kfB, kfA, qa, m, l, o, p_lds[w], lo, hi);
    }

    // epilogue: reduce deferred per-lane l over the 16 row-lanes, normalize, store
    float* op = out + (size_t)b * N_ * HD + (size_t)h * D_;
    #pragma unroll
    for (int rb = 0; rb < 2; ++rb)
        #pragma unroll
        for (int r = 0; r < 4; ++r) {
            float rs = l[rb][r];
            #pragma unroll
            for (int msk = 1; msk <= 8; msk <<= 1)
                rs += __shfl_xor(rs, msk, 64);
            float rinv = 1.f / rs;
            float* orow = op + (size_t)(q0 + rb * 16 + hi * 4 + r) * HD;
            #pragma unroll
            for (int f = 0; f < 4; ++f)
                orow[f * 16 + lo] = o[rb][f][r] * rinv;
        }
}

// ---------------- fallback (round-1 kernel) if workspace too small ----------
__global__ __launch_bounds__(256) void attn_fwd_v1(
    const float* __restrict__ q, const float* __restrict__ k,
    const float* __restrict__ v, float* __restrict__ out)
{
    const int tid  = threadIdx.x;
    const int lane = tid & 63;
    const int w    = tid >> 6;
    const int lo   = lane & 15;
    const int hi   = lane >> 4;
    const int qt   = blockIdx.x;
    const int h    = blockIdx.y;
    const int b    = blockIdx.z;

    __shared__ __align__(16) __bf16 p_lds[4][16][40];

    const size_t bh_off = (size_t)b * N_ * HD + (size_t)h * D_;
    const float* qp = q + bh_off;
    const float* kp = k + bh_off;
    const float* vp = v + bh_off;
    float*       op = out + bh_off;

    const int q0 = qt * 64 + w * 16;

    bf16x8 qa[2];
    {
        const float* qrow = qp + (size_t)(q0 + lo) * HD + hi * 8;
        #pragma unroll
        for (int kk = 0; kk < 2; ++kk)
            #pragma unroll
            for (int j = 0; j < 8; ++j)
                qa[kk][j] = (__bf16)(qrow[kk * 32 + j] * 0.125f);
    }

    float m[4], l[4];
    f32x4 o[4];
    #pragma unroll
    for (int r = 0; r < 4; ++r) { m[r] = -INFINITY; l[r] = 0.f; }
    #pragma unroll
    for (int f = 0; f < 4; ++f) o[f] = (f32x4)0.f;

    for (int kv0 = 0; kv0 < N_; kv0 += 32) {
        f32x4 s[2];
        #pragma unroll
        for (int c = 0; c < 2; ++c) {
            s[c] = (f32x4)0.f;
            const float* krow = kp + (size_t)(kv0 + c * 16 + lo) * HD + hi * 8;
            #pragma unroll
            for (int kk = 0; kk < 2; ++kk) {
                bf16x8 kbv;
                #pragma unroll
                for (int j = 0; j < 8; ++j) kbv[j] = (__bf16)krow[kk * 32 + j];
                s[c] = __builtin_amdgcn_mfma_f32_16x16x32_bf16(qa[kk], kbv, s[c], 0, 0, 0);
            }
        }
        float alpha[4], p0[4], p1[4];
        #pragma unroll
        for (int r = 0; r < 4; ++r) {
            float t = fmaxf(s[0][r], s[1][r]);
            #pragma unroll
            for (int msk = 1; msk <= 8; msk <<= 1) t = fmaxf(t, __shfl_xor(t, msk, 64));
            float mn = fmaxf(m[r], t);
            alpha[r] = __expf(m[r] - mn);
            p0[r] = __expf(s[0][r] - mn);
            p1[r] = __expf(s[1][r] - mn);
            float rs = p0[r] + p1[r];
            #pragma unroll
            for (int msk = 1; msk <= 8; msk <<= 1) rs += __shfl_xor(rs, msk, 64);
            l[r] = l[r] * alpha[r] + rs;
            m[r] = mn;
        }
        #pragma unroll
        for (int f = 0; f < 4; ++f)
            #pragma unroll
            for (int r = 0; r < 4; ++r) o[f][r] *= alpha[r];
        #pragma unroll
        for (int r = 0; r < 4; ++r) {
            p_lds[w][hi * 4 + r][lo]      = (__bf16)p0[r];
            p_lds[w][hi * 4 + r][16 + lo] = (__bf16)p1[r];
        }
        __syncthreads();
        bf16x8 pa = *(const bf16x8*)&p_lds[w][lo][hi * 8];
        #pragma unroll
        for (int f = 0; f < 4; ++f) {
            const float* vrow = vp + (size_t)(kv0 + hi * 8) * HD + f * 16 + lo;
            bf16x8 vb;
            #pragma unroll
            for (int j = 0; j < 8; ++j) vb[j] = (__bf16)vrow[(size_t)j * HD];
            o[f] = __builtin_amdgcn_mfma_f32_16x16x32_bf16(pa, vb, o[f], 0, 0, 0);
        }
        __syncthreads();
    }
    #pragma unroll
    for (int r = 0; r < 4; ++r) {
        float rinv = 1.f / l[r];
        float* orow = op + (size_t)(q0 + hi * 4 + r) * HD;
        #pragma unroll
        for (int f = 0; f < 4; ++f) orow[f * 16 + lo] = o[f][r] * rinv;
    }
}

extern "C" void kernel_launch(void* const* d_in, const int* in_sizes, int n_in,
                              void* d_out, int out_size, void* d_ws, size_t ws_size,
                              hipStream_t stream)
{
    const float* q = (const float*)d_in[0];
    const float* k = (const float*)d_in[1];
    const float* v = (const float*)d_in[2];
    float* out = (float*)d_out;

    if (ws_size >= 2 * CVT_SZ) {
        __bf16* kb = (__bf16*)d_ws;
        __bf16* vt = (__bf16*)((char*)d_ws + CVT_SZ);
        prep_kernel<<<dim3(3072), 256, 0, stream>>>(k, v, kb, vt);
        attn_fwd_v3<<<dim3(512), 256, 0, stream>>>(q, kb, vt, out);
    } else {
        attn_fwd_v1<<<dim3(N_ / 64, H_, B_), 256, 0, stream>>>(q, k, v, out);
    }
}

// Round 5
// 148.048 us; speedup vs baseline: 1.4307x; 1.4307x over previous
//
#include <hip/hip_runtime.h>
#include <hip/hip_bf16.h>
#include <math.h>

typedef __bf16 bf16x8 __attribute__((ext_vector_type(8)));
typedef float  f32x4  __attribute__((ext_vector_type(4)));

#define B_    2
#define N_    2048
#define H_    16
#define D_    64
#define HD    (H_ * D_)
#define QSCALE (0.125f * 1.44269504089f)   // 1/sqrt(64) * log2(e)
#define THR   8.0f
#define NT    32                            // kv tiles of 64
#define TILE_BYTES 16384                    // K 8KB + V 8KB per tile
#define BH_BYTES ((size_t)NT * TILE_BYTES)  // 512 KB per (b,h)
#define WS_NEED ((size_t)B_ * H_ * BH_BYTES)

#if __has_builtin(__builtin_amdgcn_exp2f)
#define EXP2F(x) __builtin_amdgcn_exp2f(x)
#else
#define EXP2F(x) __expf(0.69314718056f * (x))
#endif

// ---------------- prep: per (b,h,kv-tile) build swizzled bf16 K-tile and V^T-tile ----
// ws image per (b,h): 32 tiles x [K 8KB | V 8KB]. Within each 8KB tile (64 rows x
// 8 chunks of 16B), chunk is stored at (row*8 + (col16 ^ (row&7))) -- T2 XOR swizzle
// pre-applied so main-kernel staging is a LINEAR copy and ds_read_b128 is conflict-free.
__global__ __launch_bounds__(256) void prep_kv(
    const float* __restrict__ k, const float* __restrict__ v,
    char* __restrict__ ws)
{
    __shared__ float tile[64][68];   // V transpose buffer (68: 16B-aligned rows)
    const int tid = threadIdx.x;
    const int bid = blockIdx.x;

    if (bid < 1024) {
        // ---- K tile: [b][n][h][d] fp32 -> swizzled [row n][chunk d16] bf16 ----
        int bh = bid >> 5, t = bid & 31;
        int b = bh >> 4, h = bh & 15;
        char* dst = ws + (size_t)bh * BH_BYTES + (size_t)t * TILE_BYTES;
        #pragma unroll
        for (int p = 0; p < 2; ++p) {
            int d16 = (tid & 3) + p * 4;
            int n   = tid >> 2;
            const float* s = k + ((size_t)(b * N_ + t * 64 + n) * H_ + h) * D_ + d16 * 8;
            f32x4 a0 = *(const f32x4*)s;
            f32x4 a1 = *(const f32x4*)(s + 4);
            bf16x8 o;
            #pragma unroll
            for (int j = 0; j < 4; ++j) { o[j] = (__bf16)a0[j]; o[4 + j] = (__bf16)a1[j]; }
            int chunk = n * 8 + (d16 ^ (n & 7));
            *(bf16x8*)(dst + chunk * 16) = o;
        }
    } else {
        // ---- V tile: [b][n][h][d] fp32 -> transposed [row d][chunk n16] bf16, swizzled ----
        int vb = bid - 1024;
        int bh = vb >> 5, t = vb & 31;
        int b = bh >> 4, h = bh & 15;
        #pragma unroll
        for (int rep = 0; rep < 4; ++rep) {
            int idx = rep * 256 + tid;
            int i = idx >> 4, c4 = (idx & 15) * 4;
            *(f32x4*)&tile[i][c4] =
                *(const f32x4*)(v + ((size_t)(b * N_ + t * 64 + i) * H_ + h) * D_ + c4);
        }
        __syncthreads();
        char* dst = ws + (size_t)bh * BH_BYTES + (size_t)t * TILE_BYTES + 8192;
        #pragma unroll
        for (int rep = 0; rep < 2; ++rep) {
            int idx = rep * 256 + tid;
            int d = idx >> 3, n16 = idx & 7;
            bf16x8 o;
            #pragma unroll
            for (int j = 0; j < 8; ++j) o[j] = (__bf16)tile[n16 * 8 + j][d];
            int chunk = d * 8 + (n16 ^ (d & 7));
            *(bf16x8*)(dst + chunk * 16) = o;
        }
    }
}

// ---------------- main: 8-wave flash attention, LDS-staged double-buffered K/V ----------
__global__ __launch_bounds__(512, 4) void attn_fwd_v4(
    const float* __restrict__ q,     // original [b][n][h][d] fp32
    const char* __restrict__ ws,     // swizzled bf16 K/V tiles
    float* __restrict__ out)
{
    const int tid  = threadIdx.x;
    const int lane = tid & 63;
    const int w    = tid >> 6;       // wave 0..7
    const int lo   = lane & 15;
    const int hi   = lane >> 4;

    // bijective XCD swizzle: 512 blocks = 8 XCDs x 64; each XCD owns 4 (b,h)
    int bid = blockIdx.x;
    int wg  = (bid & 7) * 64 + (bid >> 3);
    int qt  = wg & 15;
    int bh  = wg >> 4;
    int h   = bh & 15;
    int b   = bh >> 4;

    __shared__ __align__(16) char kv_lds[2][TILE_BYTES];
    __shared__ __align__(16) __bf16 p_lds[8][16][72];

    const char* wsrc = ws + (size_t)bh * BH_BYTES;
    const int q0 = qt * 128 + w * 16;

    // Q: fp32 direct load, convert+scale inline (read once)
    bf16x8 qa[2];
    #pragma unroll
    for (int kk = 0; kk < 2; ++kk) {
        const float* qs = q + ((size_t)(b * N_ + q0 + lo) * H_ + h) * D_ + kk * 32 + hi * 8;
        f32x4 a0 = *(const f32x4*)qs;
        f32x4 a1 = *(const f32x4*)(qs + 4);
        #pragma unroll
        for (int j = 0; j < 4; ++j) {
            qa[kk][j]     = (__bf16)(a0[j] * QSCALE);
            qa[kk][4 + j] = (__bf16)(a1[j] * QSCALE);
        }
    }

    float m[4], l[4];
    f32x4 o[4];
    #pragma unroll
    for (int r = 0; r < 4; ++r) { m[r] = -INFINITY; l[r] = 0.f; }
    #pragma unroll
    for (int f = 0; f < 4; ++f) o[f] = (f32x4)0.f;

    // each wave stages 2KB of the 16KB tile image (linear copy; swizzle pre-applied)
    const int soff = w * 2048 + lane * 16;

    {   // prologue: stage tile 0
        bf16x8 s0 = *(const bf16x8*)(wsrc + soff);
        bf16x8 s1 = *(const bf16x8*)(wsrc + soff + 1024);
        *(bf16x8*)(kv_lds[0] + soff) = s0;
        *(bf16x8*)(kv_lds[0] + soff + 1024) = s1;
    }
    __syncthreads();

    for (int t = 0; t < NT; ++t) {
        const char* kbuf = kv_lds[t & 1];
        const char* vbuf = kbuf + 8192;

        // issue next-tile stage loads first (HBM/L2 latency hides under compute)
        int tn = (t + 1) & (NT - 1);
        bf16x8 s0 = *(const bf16x8*)(wsrc + (size_t)tn * TILE_BYTES + soff);
        bf16x8 s1 = *(const bf16x8*)(wsrc + (size_t)tn * TILE_BYTES + soff + 1024);

        // K frags from LDS (swizzled address -> ~2-way banks) + QK^T
        f32x4 sc[4];
        #pragma unroll
        for (int c = 0; c < 4; ++c) {
            sc[c] = (f32x4)0.f;
            #pragma unroll
            for (int kk = 0; kk < 2; ++kk) {
                int row = c * 16 + lo;
                int d16 = kk * 4 + hi;
                bf16x8 kf = *(const bf16x8*)(kbuf + row * 128 + ((d16 ^ (row & 7)) << 4));
                sc[c] = __builtin_amdgcn_mfma_f32_16x16x32_bf16(qa[kk], kf, sc[c], 0, 0, 0);
            }
        }
        // V frags issued before softmax (LDS latency hides under VALU)
        bf16x8 vf[4][2];
        #pragma unroll
        for (int f = 0; f < 4; ++f)
            #pragma unroll
            for (int s2 = 0; s2 < 2; ++s2) {
                int row = f * 16 + lo;
                int n16 = s2 * 4 + hi;
                vf[f][s2] = *(const bf16x8*)(vbuf + row * 128 + ((n16 ^ (row & 7)) << 4));
            }

        // online softmax, exp2 domain, T13 defer-max
        float pm[4];
        #pragma unroll
        for (int r = 0; r < 4; ++r)
            pm[r] = fmaxf(fmaxf(sc[0][r], sc[1][r]), fmaxf(sc[2][r], sc[3][r]));
        int ok = (pm[0] <= m[0] + THR) & (pm[1] <= m[1] + THR)
               & (pm[2] <= m[2] + THR) & (pm[3] <= m[3] + THR);
        if (!__all(ok)) {
            #pragma unroll
            for (int r = 0; r < 4; ++r) {
                float tmax = pm[r];
                #pragma unroll
                for (int msk = 1; msk <= 8; msk <<= 1)
                    tmax = fmaxf(tmax, __shfl_xor(tmax, msk, 64));
                float mn = fmaxf(m[r], tmax);
                float a  = EXP2F(m[r] - mn);
                m[r] = mn;
                l[r] *= a;
                #pragma unroll
                for (int f = 0; f < 4; ++f) o[f][r] *= a;
            }
        }
        #pragma unroll
        for (int r = 0; r < 4; ++r) {
            float p0 = EXP2F(sc[0][r] - m[r]);
            float p1 = EXP2F(sc[1][r] - m[r]);
            float p2 = EXP2F(sc[2][r] - m[r]);
            float p3 = EXP2F(sc[3][r] - m[r]);
            l[r] += (p0 + p1) + (p2 + p3);
            p_lds[w][hi * 4 + r][lo]      = (__bf16)p0;
            p_lds[w][hi * 4 + r][16 + lo] = (__bf16)p1;
            p_lds[w][hi * 4 + r][32 + lo] = (__bf16)p2;
            p_lds[w][hi * 4 + r][48 + lo] = (__bf16)p3;
        }
        // wave-synchronous P transpose (wave-private buffer, in-order LDS pipe)
        __asm__ volatile("" ::: "memory");
        bf16x8 pa0 = *(const bf16x8*)&p_lds[w][lo][hi * 8];
        bf16x8 pa1 = *(const bf16x8*)&p_lds[w][lo][32 + hi * 8];
        __asm__ volatile("" ::: "memory");

        #pragma unroll
        for (int f = 0; f < 4; ++f) {
            o[f] = __builtin_amdgcn_mfma_f32_16x16x32_bf16(pa0, vf[f][0], o[f], 0, 0, 0);
            o[f] = __builtin_amdgcn_mfma_f32_16x16x32_bf16(pa1, vf[f][1], o[f], 0, 0, 0);
        }

        // write staged regs into the other LDS buffer, one barrier per tile
        *(bf16x8*)(kv_lds[(t + 1) & 1] + soff) = s0;
        *(bf16x8*)(kv_lds[(t + 1) & 1] + soff + 1024) = s1;
        __syncthreads();
    }

    // epilogue: reduce deferred l across 16 row-lanes, normalize, store
    float* op = out + (size_t)b * N_ * HD + (size_t)h * D_;
    #pragma unroll
    for (int r = 0; r < 4; ++r) {
        float rs = l[r];
        #pragma unroll
        for (int msk = 1; msk <= 8; msk <<= 1)
            rs += __shfl_xor(rs, msk, 64);
        float rinv = 1.f / rs;
        float* orow = op + (size_t)(q0 + hi * 4 + r) * HD;
        #pragma unroll
        for (int f = 0; f < 4; ++f)
            orow[f * 16 + lo] = o[f][r] * rinv;
    }
}

// ---------------- fallback (fp32 direct) if workspace too small ----------
__global__ __launch_bounds__(256) void attn_fwd_v1(
    const float* __restrict__ q, const float* __restrict__ k,
    const float* __restrict__ v, float* __restrict__ out)
{
    const int tid  = threadIdx.x;
    const int lane = tid & 63;
    const int w    = tid >> 6;
    const int lo   = lane & 15;
    const int hi   = lane >> 4;
    const int qt   = blockIdx.x;
    const int h    = blockIdx.y;
    const int b    = blockIdx.z;

    __shared__ __align__(16) __bf16 p_lds[4][16][40];

    const size_t bh_off = (size_t)b * N_ * HD + (size_t)h * D_;
    const float* qp = q + bh_off;
    const float* kp = k + bh_off;
    const float* vp = v + bh_off;
    float*       op = out + bh_off;

    const int q0 = qt * 64 + w * 16;

    bf16x8 qa[2];
    {
        const float* qrow = qp + (size_t)(q0 + lo) * HD + hi * 8;
        #pragma unroll
        for (int kk = 0; kk < 2; ++kk)
            #pragma unroll
            for (int j = 0; j < 8; ++j)
                qa[kk][j] = (__bf16)(qrow[kk * 32 + j] * 0.125f);
    }

    float m[4], l[4];
    f32x4 o[4];
    #pragma unroll
    for (int r = 0; r < 4; ++r) { m[r] = -INFINITY; l[r] = 0.f; }
    #pragma unroll
    for (int f = 0; f < 4; ++f) o[f] = (f32x4)0.f;

    for (int kv0 = 0; kv0 < N_; kv0 += 32) {
        f32x4 s[2];
        #pragma unroll
        for (int c = 0; c < 2; ++c) {
            s[c] = (f32x4)0.f;
            const float* krow = kp + (size_t)(kv0 + c * 16 + lo) * HD + hi * 8;
            #pragma unroll
            for (int kk = 0; kk < 2; ++kk) {
                bf16x8 kbv;
                #pragma unroll
                for (int j = 0; j < 8; ++j) kbv[j] = (__bf16)krow[kk * 32 + j];
                s[c] = __builtin_amdgcn_mfma_f32_16x16x32_bf16(qa[kk], kbv, s[c], 0, 0, 0);
            }
        }
        float alpha[4], p0[4], p1[4];
        #pragma unroll
        for (int r = 0; r < 4; ++r) {
            float t = fmaxf(s[0][r], s[1][r]);
            #pragma unroll
            for (int msk = 1; msk <= 8; msk <<= 1) t = fmaxf(t, __shfl_xor(t, msk, 64));
            float mn = fmaxf(m[r], t);
            alpha[r] = __expf(m[r] - mn);
            p0[r] = __expf(s[0][r] - mn);
            p1[r] = __expf(s[1][r] - mn);
            float rs = p0[r] + p1[r];
            #pragma unroll
            for (int msk = 1; msk <= 8; msk <<= 1) rs += __shfl_xor(rs, msk, 64);
            l[r] = l[r] * alpha[r] + rs;
            m[r] = mn;
        }
        #pragma unroll
        for (int f = 0; f < 4; ++f)
            #pragma unroll
            for (int r = 0; r < 4; ++r) o[f][r] *= alpha[r];
        #pragma unroll
        for (int r = 0; r < 4; ++r) {
            p_lds[w][hi * 4 + r][lo]      = (__bf16)p0[r];
            p_lds[w][hi * 4 + r][16 + lo] = (__bf16)p1[r];
        }
        __syncthreads();
        bf16x8 pa = *(const bf16x8*)&p_lds[w][lo][hi * 8];
        #pragma unroll
        for (int f = 0; f < 4; ++f) {
            const float* vrow = vp + (size_t)(kv0 + hi * 8) * HD + f * 16 + lo;
            bf16x8 vb;
            #pragma unroll
            for (int j = 0; j < 8; ++j) vb[j] = (__bf16)vrow[(size_t)j * HD];
            o[f] = __builtin_amdgcn_mfma_f32_16x16x32_bf16(pa, vb, o[f], 0, 0, 0);
        }
        __syncthreads();
    }
    #pragma unroll
    for (int r = 0; r < 4; ++r) {
        float rinv = 1.f / l[r];
        float* orow = op + (size_t)(q0 + hi * 4 + r) * HD;
        #pragma unroll
        for (int f = 0; f < 4; ++f) orow[f * 16 + lo] = o[f][r] * rinv;
    }
}

extern "C" void kernel_launch(void* const* d_in, const int* in_sizes, int n_in,
                              void* d_out, int out_size, void* d_ws, size_t ws_size,
                              hipStream_t stream)
{
    const float* q = (const float*)d_in[0];
    const float* k = (const float*)d_in[1];
    const float* v = (const float*)d_in[2];
    float* out = (float*)d_out;

    if (ws_size >= WS_NEED) {
        char* ws = (char*)d_ws;
        prep_kv<<<dim3(2048), 256, 0, stream>>>(k, v, ws);
        attn_fwd_v4<<<dim3(512), 512, 0, stream>>>(q, ws, out);
    } else {
        attn_fwd_v1<<<dim3(N_ / 64, H_, B_), 256, 0, stream>>>(q, k, v, out);
    }
}